// Round 4
// baseline (122.513 us; speedup 1.0000x reference)
//
#include <hip/hip_runtime.h>

// CSPN-style spatially-varying 7x7 filter.
// out[b,y,x] = sum_{i,j} gw[b, 7i+j, y+3, x+3] * src[b, y+3-i, x+3-j]
// src = hn except tap t==24 (i=j=3) which uses h0[b,y,x].
// Out-of-range hn reads are zero.
//
// R4: alignment-phased quads (R3 with the tail-guard bug fixed).
// gw word offset for pixel x is b*49*PLANE + (y+3)*518 + 3 + x and
// PLANE % 4 == 0, so per row a phase a0 in {1,3} makes quads x0 = a0 + 4k
// 16B-aligned for ALL 49 taps -> aligned global_load_dwordx4 streams.
// hn window loads are range-guarded exactly: wA iff x0<4, wB iff x0+3>=W,
// wC iff x0+7>=W (R3 faulted: k==126 at a0==3 read 3 floats past hn).

constexpr int B = 8, H = 512, W = 512, K = 7, HP = H + K - 1; // 518
constexpr long PLANE = (long)HP * HP;                          // 268324 (mult of 4)

__global__ __launch_bounds__(256) void cspn_kernel(
    const float* __restrict__ gw, const float* __restrict__ hn,
    const float* __restrict__ h0, float* __restrict__ out)
{
    int q = blockIdx.x * 256 + threadIdx.x;   // quad slot
    int k = q & 127;                          // quad index within row
    int row = q >> 7;                         // 0..4095
    int y = row & 511;
    int b = row >> 9;

    long R = (long)(y + 3) * HP + 3;          // gw word offset of pixel 0 (in-plane)
    int a0 = (4 - (int)(R & 3)) & 3;          // 1 or 3: aligned phase
    int x0 = a0 + (k << 2);                   // this thread's quad start pixel (<=511)

    const float* gbase = gw + (size_t)b * 49 * PLANE + R + x0;  // tap 0, 16B-aligned
    const float* hb = hn + (size_t)b * H * W;
    const float* h0row = h0 + ((size_t)b * H + y) * W;
    float* orow = out + ((size_t)b * H + y) * W;

    // h0 for pixels x0..x0+3 (xp may exceed 511 near the row end)
    float hv[4];
    #pragma unroll
    for (int c = 0; c < 4; ++c) {
        int xp = x0 + c;
        hv[c] = (xp < W) ? h0row[xp] : 0.f;
    }

    float acc[4] = {0.f, 0.f, 0.f, 0.f};

    #pragma unroll
    for (int i = 0; i < K; ++i) {
        int sy = y + 3 - i;
        bool oky = (unsigned)sy < (unsigned)H;            // wave-uniform
        const float* hrow = hb + (size_t)(oky ? sy : 0) * W;

        // window w[u] = hn[sy, x0-4+u], u=0..11, zero outside [0,W)
        float w[12];
        if (!oky) {
            #pragma unroll
            for (int u = 0; u < 12; ++u) w[u] = 0.f;
        } else {
            if (x0 >= 4) {                                 // wA: cols x0-4..x0-1
                float4 wA = *reinterpret_cast<const float4*>(hrow + x0 - 4);
                w[0] = wA.x; w[1] = wA.y; w[2] = wA.z; w[3] = wA.w;
            } else {
                #pragma unroll
                for (int u = 0; u < 4; ++u) {
                    int col = x0 - 4 + u;
                    w[u] = (col >= 0) ? hrow[col] : 0.f;
                }
            }
            if (x0 + 3 < W) {                              // wB: cols x0..x0+3
                float4 wB = *reinterpret_cast<const float4*>(hrow + x0);
                w[4] = wB.x; w[5] = wB.y; w[6] = wB.z; w[7] = wB.w;
            } else {
                #pragma unroll
                for (int u = 4; u < 8; ++u) {
                    int col = x0 - 4 + u;
                    w[u] = (col < W) ? hrow[col] : 0.f;
                }
            }
            if (x0 + 7 < W) {                              // wC: cols x0+4..x0+7
                float4 wC = *reinterpret_cast<const float4*>(hrow + x0 + 4);
                w[8] = wC.x; w[9] = wC.y; w[10] = wC.z; w[11] = wC.w;
            } else {
                #pragma unroll
                for (int u = 8; u < 12; ++u) {
                    int col = x0 - 4 + u;
                    w[u] = (col < W) ? hrow[col] : 0.f;
                }
            }
        }

        #pragma unroll
        for (int j = 0; j < K; ++j) {
            int t = i * K + j;
            float4 g = *reinterpret_cast<const float4*>(gbase + (size_t)t * PLANE);
            if (t == 24) {
                acc[0] += g.x * hv[0];
                acc[1] += g.y * hv[1];
                acc[2] += g.z * hv[2];
                acc[3] += g.w * hv[3];
            } else {
                acc[0] += g.x * w[7 - j];
                acc[1] += g.y * w[8 - j];
                acc[2] += g.z * w[9 - j];
                acc[3] += g.w * w[10 - j];
            }
        }
    }

    #pragma unroll
    for (int c = 0; c < 4; ++c) {
        int xp = x0 + c;
        if (xp < W) orow[xp] = acc[c];
    }

    // leading edge pixels 0..a0-1: one per lane k < a0, scalar path
    if (k < a0) {
        int xe = k;
        const float* geb = gw + (size_t)b * 49 * PLANE + R + xe;
        float accE = 0.f;
        #pragma unroll
        for (int i = 0; i < K; ++i) {
            int sy = y + 3 - i;
            bool oky = (unsigned)sy < (unsigned)H;
            const float* hrow = hb + (size_t)(oky ? sy : 0) * W;
            #pragma unroll
            for (int j = 0; j < K; ++j) {
                int t = i * K + j;
                float g = geb[(size_t)t * PLANE];
                float v;
                if (t == 24) {
                    v = h0row[xe];
                } else {
                    int col = xe + 3 - j;
                    v = (oky && (unsigned)col < (unsigned)W) ? hrow[col] : 0.f;
                }
                accE += g * v;
            }
        }
        orow[xe] = accE;
    }
}

extern "C" void kernel_launch(void* const* d_in, const int* in_sizes, int n_in,
                              void* d_out, int out_size, void* d_ws, size_t ws_size,
                              hipStream_t stream)
{
    const float* gw = (const float*)d_in[0];
    const float* hn = (const float*)d_in[1];
    const float* h0 = (const float*)d_in[2];
    float* out = (float*)d_out;

    int quads = B * H * 128;               // 524288 quad slots
    int blocks = quads / 256;              // 2048
    cspn_kernel<<<blocks, 256, 0, stream>>>(gw, hn, h0, out);
}

// Round 5
// 83.892 us; speedup vs baseline: 1.4604x; 1.4604x over previous
//
#include <hip/hip_runtime.h>

// CSPN-style spatially-varying 7x7 filter.
// out[b,y,x] = sum_{i,j in [0,7)} gw[b, 7i+j, y+3, x+3] * src[b, y+3-i, x+3-j]
// src = hn except tap t==24 (i=j=3) which uses h0[b,y,x].
// Out-of-range hn reads are zero.
//
// R5: R1's scalar 1-px/thread structure (best so far, 83.4 us) with two
// memory-system changes:
//  - block=1024: one block spans 2 consecutive image rows, so each of the 49
//    gw tap-streams is consumed in ~4.1 KB contiguous runs per block
//    (vs 1 KB), improving DRAM row-buffer locality at the MCs.
//  - nontemporal loads on gw + nontemporal store on out: gw is 420 MB
//    stream-once data; early-eviction hints keep it from thrashing L2/L3
//    where hn/h0 (8.4 MB each, 49x-reused) live.
// Wide loads deliberately NOT used: R2/R4 showed 4-px/thread float4 variants
// lose to scalar (register pressure + 4x fewer waves), not alignment.

constexpr int B = 8, H = 512, W = 512, K = 7, HP = H + K - 1; // 518
constexpr long PLANE = (long)HP * HP;                          // 268324

__global__ __launch_bounds__(1024) void cspn_kernel(
    const float* __restrict__ gw, const float* __restrict__ hn,
    const float* __restrict__ h0, float* __restrict__ out)
{
    int tid = blockIdx.x * 1024 + threadIdx.x;
    int x = tid & (W - 1);          // 9 bits
    int y = (tid >> 9) & (H - 1);   // 9 bits
    int b = tid >> 18;

    // gw pointer for tap 0 at this pixel; tap t is at +t*PLANE.
    const float* gp = gw + (size_t)b * 49 * PLANE + (size_t)(y + 3) * HP + (x + 3);
    const float* hb = hn + (size_t)b * H * W;

    float acc = 0.f;
    #pragma unroll
    for (int i = 0; i < K; ++i) {
        int sy = y + 3 - i;                       // source row for this tap row
        bool oky = (unsigned)sy < (unsigned)H;    // wave-uniform guard
        const float* hrow = hb + (size_t)(oky ? sy : 0) * W;
        #pragma unroll
        for (int j = 0; j < K; ++j) {
            int t = i * K + j;
            float g = __builtin_nontemporal_load(gp + (size_t)t * PLANE);
            float v;
            if (t == 24) {
                // center tap: h0 at (y, x), always in-bounds
                v = h0[((size_t)b * H + y) * W + x];
            } else {
                int sx = x + 3 - j;
                bool ok = oky && ((unsigned)sx < (unsigned)W);
                v = ok ? hrow[sx] : 0.f;
            }
            acc += g * v;
        }
    }
    __builtin_nontemporal_store(acc, out + ((size_t)b * H + y) * W + x);
}

extern "C" void kernel_launch(void* const* d_in, const int* in_sizes, int n_in,
                              void* d_out, int out_size, void* d_ws, size_t ws_size,
                              hipStream_t stream)
{
    const float* gw = (const float*)d_in[0];
    const float* hn = (const float*)d_in[1];
    const float* h0 = (const float*)d_in[2];
    float* out = (float*)d_out;

    int total = B * H * W;                 // 2,097,152 outputs
    int blocks = total / 1024;             // 2048
    cspn_kernel<<<blocks, 1024, 0, stream>>>(gw, hn, h0, out);
}